// Round 8
// baseline (250.030 us; speedup 1.0000x reference)
//
#include <hip/hip_runtime.h>
#include <math.h>

#define DD 768
#define HH 16
#define DHH 48
#define NPOS 512
#define NIDX 2048
#define INV_SCALE 0.14433756729740643f   // 1/sqrt(768/16)
#define LN_EPS 1e-5f

typedef __bf16 bf16_t;
typedef __bf16 bf16x8 __attribute__((ext_vector_type(8)));
typedef float f32x4 __attribute__((ext_vector_type(4)));

__device__ __forceinline__ void g2lds16(const void* g, void* l) {
  __builtin_amdgcn_global_load_lds((const __attribute__((address_space(1))) void*)g,
                                   (__attribute__((address_space(3))) void*)l, 16, 0, 0);
}
// staging bank-swizzle: lane L of a 16-row issue block fetches 8-elem chunk
// (L&3)^((L>>3)&3); reader at (row, lq) finds chunk lq at position lq^((row>>1)&3).
__device__ __forceinline__ int stg_chunk(int lane) { return (lane & 3) ^ ((lane >> 3) & 3); }
__device__ __forceinline__ int rd_off(int row, int lq) {
  return row * 32 + ((lq ^ ((row >> 1) & 3)) << 3);
}

// ---------------------------------------------------------------------------
// prep: blocks 0-5 hist | rest: fp32->bf16 cvt (src=null -> zero fill)
// ---------------------------------------------------------------------------
struct CvtDesc { const float* src; bf16_t* dst; int n8; };
struct CvtBatch { CvtDesc d[13]; };

__global__ __launch_bounds__(256) void prep(const int* __restrict__ fpos,
                                            const int* __restrict__ tpos,
                                            int* __restrict__ CNT, CvtBatch cvb) {
  const int bid = blockIdx.x;
  const int tid = threadIdx.x;
  __shared__ int shist[NPOS];
  if (bid < 6) {
    const int b = bid >> 1, which = bid & 1;
    const int* src = (which ? tpos : fpos) + b * NIDX;
    for (int i = tid; i < NPOS; i += 256) shist[i] = 0;
    __syncthreads();
    for (int i = tid; i < NIDX; i += 256) atomicAdd(&shist[src[i] & (NPOS - 1)], 1);
    __syncthreads();
    for (int i = tid; i < NPOS; i += 256) CNT[bid * NPOS + i] = shist[i];
    return;
  }
  const CvtDesc de = cvb.d[(bid - 6) >> 6];
  for (int i = ((bid - 6) & 63) * 256 + tid; i < de.n8; i += 64 * 256) {
    bf16_t t[8];
    if (de.src) {
      const f32x4 a = *(const f32x4*)(de.src + (size_t)i * 8);
      const f32x4 b = *(const f32x4*)(de.src + (size_t)i * 8 + 4);
#pragma unroll
      for (int e = 0; e < 4; ++e) { t[e] = (bf16_t)a[e]; t[4 + e] = (bf16_t)b[e]; }
    } else {
#pragma unroll
      for (int e = 0; e < 8; ++e) t[e] = (bf16_t)0.f;
    }
    *(bf16x8*)(de.dst + (size_t)i * 8) = *(bf16x8*)t;
  }
}

// ---------------------------------------------------------------------------
// MFMA GEMM, 64x128 tile, dbuf single-barrier, swizzled staging.
// mode: 0 f32 out | 1 bf16 out | 2 bf16 transposed (C[c*512+r]) |
//       3 K-aug: c<768 -> bf16 C; 768<=c<784 -> f32 cb[r*16+c-768]
// ---------------------------------------------------------------------------
struct MDesc { const bf16_t* A; const bf16_t* B; const float* bias; void* C;
               float* cb; int mode; int ntiles; };
struct MBatch { MDesc d[18]; };

__global__ __launch_bounds__(256, 4) void gemm64(MBatch batch) {
  const MDesc de = batch.d[blockIdx.y];
  const int mt = blockIdx.x & 7, nt = blockIdx.x >> 3;   // 8 x up-to-7
  if (nt >= de.ntiles) return;
  const int m0 = mt * 64, n0 = nt * 128;

  __shared__ bf16_t SA[2][2048];   // [64][32] packed (swizzled chunks)
  __shared__ bf16_t SB[2][4096];   // [128][32]

  const int tid = threadIdx.x;
  const int w = tid >> 6, lane = tid & 63;
  const int wm = w >> 1, wn = w & 1;
  const int lm = lane & 15, lq = lane >> 4;
  const int sr = lane >> 2, sc = stg_chunk(lane);

  f32x4 acc[2][4] = {};

  auto stage = [&](int buf, int k0) {
#pragma unroll
    for (int c = 0; c < 3; ++c) {
      const int issue = w + c * 4;           // 0..11, wave-uniform
      if (issue < 4)
        g2lds16(de.A + (size_t)(m0 + issue * 16 + sr) * 768 + k0 + sc * 8,
                SA[buf] + issue * 512);
      else {
        const int e = issue - 4;
        g2lds16(de.B + (size_t)(n0 + e * 16 + sr) * 768 + k0 + sc * 8,
                SB[buf] + e * 512);
      }
    }
  };

  stage(0, 0);
  for (int k0i = 0; k0i < 24; ++k0i) {
    const int cur = k0i & 1;
    __syncthreads();
    if (k0i + 1 < 24) stage(cur ^ 1, (k0i + 1) * 32);
    bf16x8 af[2], bfr[4];
#pragma unroll
    for (int i = 0; i < 2; ++i)
      af[i] = *(const bf16x8*)(SA[cur] + rd_off(wm * 32 + i * 16 + lm, lq));
#pragma unroll
    for (int j = 0; j < 4; ++j)
      bfr[j] = *(const bf16x8*)(SB[cur] + rd_off(wn * 64 + j * 16 + lm, lq));
#pragma unroll
    for (int i = 0; i < 2; ++i)
#pragma unroll
      for (int j = 0; j < 4; ++j)
        acc[i][j] = __builtin_amdgcn_mfma_f32_16x16x32_bf16(af[i], bfr[j], acc[i][j], 0, 0, 0);
  }

#pragma unroll
  for (int i = 0; i < 2; ++i) {
    const int rbase = m0 + wm * 32 + i * 16 + lq * 4;
#pragma unroll
    for (int j = 0; j < 4; ++j) {
      const int c = n0 + wn * 64 + j * 16 + lm;
      const float bv = (de.bias && c < 768) ? de.bias[c] : 0.f;
#pragma unroll
      for (int r = 0; r < 4; ++r) {
        const float v = acc[i][j][r] + bv;
        if (de.mode == 0)      ((float*)de.C)[(size_t)(rbase + r) * 768 + c] = v;
        else if (de.mode == 1) ((bf16_t*)de.C)[(size_t)(rbase + r) * 768 + c] = (bf16_t)v;
        else if (de.mode == 2) ((bf16_t*)de.C)[(size_t)c * NPOS + rbase + r] = (bf16_t)v;
        else {
          if (c < 768)       ((bf16_t*)de.C)[(size_t)(rbase + r) * 768 + c] = (bf16_t)v;
          else if (c < 784)  de.cb[(size_t)(rbase + r) * 16 + (c - 768)] = v;
        }
      }
    }
  }
}

// ---------------------------------------------------------------------------
// Fused MFMA attention, single k-pass, head-sharing.
// Block = (pd, 2 heads, 32 f-rows), 512 threads / 8 waves.
// Wave w = (hh = w&1, jq = w>>1): S strip 32f x 128j in regs (64 VGPR).
// K (all 512 j) + Q staged once per k0, shared by all waves; mix applied at
// A-fragment ONCE per Q element. Then 2 head-phases: exp->P (reusing the
// staging LDS), PV via MFMA with ones-row denominator.
// ---------------------------------------------------------------------------
__global__ __launch_bounds__(512, 4) void attn_mfma(
    const bf16_t* __restrict__ Qg, const bf16_t* __restrict__ Kg,
    const bf16_t* __restrict__ Vt, const float* __restrict__ cbG,
    const int* __restrict__ CNT, const float* __restrict__ mix0,
    const float* __restrict__ mix1, bf16_t* __restrict__ CTX) {
  const int bid = blockIdx.x;             // 6*8*16 = 768, pd-major
  const int pd = bid >> 7;
  const int hg = (bid >> 4) & 7;          // head group: heads hg*2, hg*2+1
  const int ft = bid & 15;
  const int dir = pd & 1;
  const int f0 = ft * 32;

  // U: k-loop staging { Q 32x32 @0 (1024 elems), K 512x32 @1024 (16384) }
  //    phase reuse:   P (32 x 532) = 17024 elems
  __shared__ bf16_t U[17408];
  __shared__ bf16_t Vs[64 * 264];         // [c-row][j], rows 0-47 V, 48 ones, 49+ zero
  __shared__ float mixs[2][768];          // pre-scaled by INV_SCALE
  __shared__ float cbw[2][512];           // cb*inv + log(cnt)
  __shared__ float rowl[2][32];

  const int tid = threadIdx.x;
  const int w = tid >> 6, lane = tid & 63;
  const int hh = w & 1, jq = w >> 1;
  const int lm = lane & 15, lq = lane >> 4;
  const int sr = lane >> 2, sc = stg_chunk(lane);

  const bf16_t* Qp = Qg + (size_t)pd * NPOS * DD;
  const bf16_t* Kp = Kg + (size_t)pd * NPOS * DD;
  const float* mixsel = dir ? mix1 : mix0;
  const int* cnt = CNT + ((pd & ~1) + (1 - dir)) * NPOS;  // to-side counts

  for (int i = tid; i < 2 * 768; i += 512) {
    const int h2 = i / 768, c = i % 768;
    mixs[h2][c] = mixsel[(hg * 2 + h2) * DD + c] * INV_SCALE;
  }
  for (int i = tid; i < 2 * 512; i += 512) {
    const int h2 = i >> 9, j = i & 511;
    cbw[h2][j] = cbG[((size_t)pd * NPOS + j) * HH + hg * 2 + h2] * INV_SCALE
               + __logf((float)cnt[j]);
  }
  // Vs static rows 48..63 (ones row + zero pad) — set once
  for (int i = tid; i < 16 * 264; i += 512) {
    const int r = 48 + i / 264, c = i % 264;
    Vs[r * 264 + c] = (bf16_t)((r == 48 && c < 256) ? 1.f : 0.f);
  }

  f32x4 sa[2][8] = {};   // [f-frag][j-frag], wave strip 32f x 128j

  for (int k0i = 0; k0i < 24; ++k0i) {
    const int k0 = k0i * 32;
    __syncthreads();                  // prev compute done (iter0: init done)
#pragma unroll
    for (int c = 0; c < 5; ++c) {
      const int issue = w + c * 8;    // 0..39, wave-uniform; 0,1=Q, 2..33=K
      if (issue < 2)
        g2lds16(Qp + (size_t)(f0 + issue * 16 + sr) * DD + k0 + sc * 8,
                U + issue * 512);
      else if (issue < 34) {
        const int e = issue - 2;
        g2lds16(Kp + (size_t)(e * 16 + sr) * DD + k0 + sc * 8,
                U + 1024 + e * 512);
      }
    }
    __syncthreads();                  // g2lds drained

    const f32x4 mxa = *(const f32x4*)&mixs[hh][k0 + lq * 8];
    const f32x4 mxb = *(const f32x4*)&mixs[hh][k0 + lq * 8 + 4];
    bf16x8 af[2];
#pragma unroll
    for (int i = 0; i < 2; ++i) {
      const bf16x8 q = *(const bf16x8*)(U + rd_off(i * 16 + lm, lq));
      bf16_t t[8];
#pragma unroll
      for (int e = 0; e < 4; ++e) {
        t[e]     = (bf16_t)((float)q[e] * mxa[e]);
        t[4 + e] = (bf16_t)((float)q[4 + e] * mxb[e]);
      }
      af[i] = *(bf16x8*)t;
    }
#pragma unroll
    for (int jj = 0; jj < 8; ++jj) {
      const bf16x8 bf = *(const bf16x8*)(U + 1024 + rd_off(jq * 128 + jj * 16 + lm, lq));
      sa[0][jj] = __builtin_amdgcn_mfma_f32_16x16x32_bf16(af[0], bf, sa[0][jj], 0, 0, 0);
      sa[1][jj] = __builtin_amdgcn_mfma_f32_16x16x32_bf16(af[1], bf, sa[1][jj], 0, 0, 0);
    }
  }
  __syncthreads();                    // k-loop reads done; U becomes P

  // ---- two head phases: exp -> P, then PV with ones-row denominator ----
  const int fi = w & 1, cj = w >> 1;  // PV tile assignment (8 tiles: 2f x 4c)
  f32x4 pv[2] = {};

  for (int ph = 0; ph < 2; ++ph) {
    const int h = hg * 2 + ph;
    const bf16_t* Vp = Vt + (size_t)pd * DD * NPOS + (size_t)h * DHH * NPOS;

    if (hh == ph) {                   // owner waves write P = exp(sa + cbw)
#pragma unroll
      for (int jj = 0; jj < 8; ++jj) {
        const int col = jq * 128 + jj * 16 + lm;
        const float cb = cbw[ph][col];
#pragma unroll
        for (int i = 0; i < 2; ++i) {
          const int rb = i * 16 + lq * 4;
#pragma unroll
          for (int r = 0; r < 4; ++r)
            U[(rb + r) * 532 + col] = (bf16_t)__expf(sa[i][jj][r] + cb);
        }
      }
    }

    for (int vh = 0; vh < 2; ++vh) {  // PV over two 256-j halves
      // stage Vs rows 0..47 for this half
      for (int i = tid; i < 48 * 32; i += 512) {
        const int r = i >> 5, cc = i & 31;
        *(bf16x8*)(Vs + r * 264 + cc * 8) =
            *(const bf16x8*)(Vp + (size_t)r * NPOS + vh * 256 + cc * 8);
      }
      __syncthreads();                // exp-writes + Vs stage visible
#pragma unroll
      for (int kk = 0; kk < 8; ++kk) {
        const bf16x8 pa = *(const bf16x8*)(U + (fi * 16 + lm) * 532 + vh * 256 + kk * 32 + lq * 8);
        const bf16x8 pb = *(const bf16x8*)(Vs + (cj * 16 + lm) * 264 + kk * 32 + lq * 8);
        pv[ph] = __builtin_amdgcn_mfma_f32_16x16x32_bf16(pa, pb, pv[ph], 0, 0, 0);
      }
      __syncthreads();                // PV reads done before next stage/exp
    }
    if (cj == 3 && lm == 0) {         // col 48 = row denominator
#pragma unroll
      for (int r = 0; r < 4; ++r) rowl[ph][fi * 16 + lq * 4 + r] = pv[ph][r];
    }
  }
  __syncthreads();

  // ---- epilogue: ctx = pv / l ----
  if (cj < 3) {
#pragma unroll
    for (int ph = 0; ph < 2; ++ph) {
      const int h = hg * 2 + ph;
#pragma unroll
      for (int r = 0; r < 4; ++r) {
        const int fr = fi * 16 + lq * 4 + r;
        CTX[((size_t)pd * NPOS + f0 + fr) * DD + h * DHH + cj * 16 + lm] =
            (bf16_t)(pv[ph][r] / rowl[ph][fr]);
      }
    }
  }
}

// ---------------------------------------------------------------------------
// Residual + LayerNorm + count-weighted mean -> out[b][dir*768 .. +768]
// ---------------------------------------------------------------------------
__global__ __launch_bounds__(256) void ln_mean_kernel(
    const float* __restrict__ hs, const float* __restrict__ XB,
    const int* __restrict__ CNT,
    const float* __restrict__ lng0, const float* __restrict__ lnb0,
    const float* __restrict__ lng1, const float* __restrict__ lnb1,
    float* __restrict__ out) {
  const int blk = blockIdx.x;          // (b*2+dir)*64 + chunk, 384 blocks
  const int chunk = blk & 63;
  const int pd = blk >> 6;
  const int b = pd >> 1, dir = pd & 1;
  const float* lng = dir ? lng1 : lng0;
  const float* lnb = dir ? lnb1 : lnb0;
  const int* cnt = CNT + pd * NPOS;    // from-side counts
  const float* hb = hs + (size_t)b * NPOS * DD;
  const float* xb = XB + (size_t)pd * NPOS * DD;

  __shared__ float wacc[4][DD];
  const int tid = threadIdx.x;
  const int wave = tid >> 6, lane = tid & 63;
  for (int d0 = tid; d0 < 4 * DD; d0 += 256) ((float*)wacc)[d0] = 0.f;
  __syncthreads();

  float lg[12], lb[12];
#pragma unroll
  for (int qd = 0; qd < 12; ++qd) {
    lg[qd] = lng[lane + qd * 64];
    lb[qd] = lnb[lane + qd * 64];
  }

  for (int rr = 0; rr < 2; ++rr) {
    const int p = chunk * 8 + wave * 2 + rr;
    float x[12];
    float s = 0.f, ss = 0.f;
#pragma unroll
    for (int qd = 0; qd < 12; ++qd) {
      const int d0 = lane + qd * 64;
      const float xv = hb[(size_t)p * DD + d0] + xb[(size_t)p * DD + d0];
      x[qd] = xv; s += xv; ss += xv * xv;
    }
#pragma unroll
    for (int o = 1; o < 64; o <<= 1) {
      s += __shfl_xor(s, o);
      ss += __shfl_xor(ss, o);
    }
    const float mu = s * (1.f / 768.f);
    const float var = ss * (1.f / 768.f) - mu * mu;
    const float rstd = rsqrtf(var + LN_EPS);
    const float wgt = (float)cnt[p];
    if (wgt != 0.f) {
#pragma unroll
      for (int qd = 0; qd < 12; ++qd) {
        const int d0 = lane + qd * 64;
        wacc[wave][d0] += wgt * (lg[qd] * (x[qd] - mu) * rstd + lb[qd]);
      }
    }
  }
  __syncthreads();
  for (int d0 = tid; d0 < DD; d0 += 256) {
    const float t = wacc[0][d0] + wacc[1][d0] + wacc[2][d0] + wacc[3][d0];
    atomicAdd(&out[b * 1536 + dir * 768 + d0], t * (1.f / 2048.f));
  }
}

// ---------------------------------------------------------------------------
extern "C" void kernel_launch(void* const* d_in, const int* in_sizes, int n_in,
                              void* d_out, int out_size, void* d_ws, size_t ws_size,
                              hipStream_t stream) {
  const float* hs  = (const float*)d_in[0];
  const int* fpos  = (const int*)d_in[1];
  const int* tpos  = (const int*)d_in[2];

  const float* Wq[2]; const float* Wk[2]; const float* Wcb[2]; const float* Wv[2];
  const float* Wd[2]; const float* mixp[2];
  const float* bv[2]; const float* bd[2]; const float* lng[2]; const float* lnb[2];
  for (int p = 0; p < 2; ++p) {
    const int base = 3 + p * 10;
    Wq[p]   = (const float*)d_in[base + 0];
    Wk[p]   = (const float*)d_in[base + 1];
    Wcb[p]  = (const float*)d_in[base + 2];
    Wv[p]   = (const float*)d_in[base + 3];
    Wd[p]   = (const float*)d_in[base + 4];
    mixp[p] = (const float*)d_in[base + 5];
    bv[p]   = (const float*)d_in[base + 6];
    bd[p]   = (const float*)d_in[base + 7];
    lng[p]  = (const float*)d_in[base + 8];
    lnb[p]  = (const float*)d_in[base + 9];
  }

  char* wsp = (char*)d_ws;
  size_t off = 0;
  auto alloc = [&](size_t bytes) { char* p = wsp + off; off = (off + bytes + 255) & ~(size_t)255; return p; };
  bf16_t* hsb  = (bf16_t*)alloc((size_t)3 * NPOS * DD * 2);
  bf16_t* Wb   = (bf16_t*)alloc((size_t)6 * DD * DD * 2);     // Wq0,Wv0,Wd0,Wq1,Wv1,Wd1
  bf16_t* WkCb = (bf16_t*)alloc((size_t)2 * 896 * DD * 2);    // [Wk;Wcb;pad] per pset
  bf16_t* Qbf  = (bf16_t*)alloc((size_t)6 * NPOS * DD * 2);
  bf16_t* Kbf  = (bf16_t*)alloc((size_t)6 * NPOS * DD * 2);
  bf16_t* VtG  = (bf16_t*)alloc((size_t)6 * DD * NPOS * 2);
  bf16_t* CTXb = (bf16_t*)alloc((size_t)6 * NPOS * DD * 2);
  float*  XB   = (float*) alloc((size_t)6 * NPOS * DD * 4);
  float*  cbG  = (float*) alloc((size_t)6 * NPOS * HH * 4);
  int*    CNTb = (int*)   alloc((size_t)6 * NPOS * 4);

  hipMemsetAsync(d_out, 0, (size_t)out_size * sizeof(float), stream);

  CvtBatch cvb{};
  cvb.d[0] = CvtDesc{hs, hsb, 3 * NPOS * DD / 8};
  for (int p = 0; p < 2; ++p) {
    cvb.d[1 + p * 3] = CvtDesc{Wq[p], Wb + (size_t)(p * 3 + 0) * DD * DD, DD * DD / 8};
    cvb.d[2 + p * 3] = CvtDesc{Wv[p], Wb + (size_t)(p * 3 + 1) * DD * DD, DD * DD / 8};
    cvb.d[3 + p * 3] = CvtDesc{Wd[p], Wb + (size_t)(p * 3 + 2) * DD * DD, DD * DD / 8};
    bf16_t* wk = WkCb + (size_t)p * 896 * DD;
    cvb.d[7 + p * 3] = CvtDesc{Wk[p], wk, DD * DD / 8};
    cvb.d[8 + p * 3] = CvtDesc{Wcb[p], wk + (size_t)768 * DD, 16 * DD / 8};
    cvb.d[9 + p * 3] = CvtDesc{nullptr, wk + (size_t)784 * DD, 112 * DD / 8};
  }
  prep<<<838, 256, 0, stream>>>(fpos, tpos, CNTb, cvb);

  // projection GEMMs: Q bf16, K' (K + content bias), V bf16-transposed
  MBatch gb{};
  int n = 0;
  for (int b = 0; b < 3; ++b)
    for (int p = 0; p < 2; ++p) {
      const int pd = b * 2 + p;
      const bf16_t* A = hsb + (size_t)b * NPOS * DD;
      const size_t o = (size_t)pd * NPOS * DD;
      gb.d[n++] = MDesc{A, Wb + (size_t)(p * 3 + 0) * DD * DD, nullptr, Qbf + o, nullptr, 1, 6};
      gb.d[n++] = MDesc{A, WkCb + (size_t)p * 896 * DD, nullptr, Kbf + o,
                        cbG + (size_t)pd * NPOS * HH, 3, 7};
      gb.d[n++] = MDesc{A, Wb + (size_t)(p * 3 + 1) * DD * DD, bv[p],
                        VtG + (size_t)pd * DD * NPOS, nullptr, 2, 6};
    }
  gemm64<<<dim3(56, 18), 256, 0, stream>>>(gb);

  attn_mfma<<<768, 512, 0, stream>>>(Qbf, Kbf, VtG, cbG, CNTb, mixp[0], mixp[1], CTXb);

  MBatch gd{};
  for (int b = 0; b < 3; ++b)
    for (int p = 0; p < 2; ++p) {
      const int pd = b * 2 + p;
      const size_t o = (size_t)pd * NPOS * DD;
      gd.d[pd] = MDesc{CTXb + o, Wb + (size_t)(p * 3 + 2) * DD * DD, bd[p],
                       XB + o, nullptr, 0, 6};
    }
  gemm64<<<dim3(56, 6), 256, 0, stream>>>(gd);

  ln_mean_kernel<<<384, 256, 0, stream>>>(hs, XB, CNTb, lng[0], lnb[0], lng[1], lnb[1],
                                          (float*)d_out);
}

// Round 9
// 236.133 us; speedup vs baseline: 1.0589x; 1.0589x over previous
//
#include <hip/hip_runtime.h>
#include <math.h>

#define DD 768
#define HH 16
#define DHH 48
#define NPOS 512
#define NIDX 2048
#define INV_SCALE 0.14433756729740643f   // 1/sqrt(768/16)
#define LN_EPS 1e-5f

typedef __bf16 bf16_t;
typedef __bf16 bf16x8 __attribute__((ext_vector_type(8)));
typedef float f32x4 __attribute__((ext_vector_type(4)));

__device__ __forceinline__ void g2lds16(const void* g, void* l) {
  __builtin_amdgcn_global_load_lds((const __attribute__((address_space(1))) void*)g,
                                   (__attribute__((address_space(3))) void*)l, 16, 0, 0);
}
// staging bank-swizzle: lane L of a 16-row issue block holds 8-elem chunk
// (L&3)^((L>>3)&3); reader at (row, lq) finds chunk lq at position lq^((row>>1)&3).
__device__ __forceinline__ int stg_chunk(int lane) { return (lane & 3) ^ ((lane >> 3) & 3); }
__device__ __forceinline__ int rd_off(int row, int lq) {
  return row * 32 + ((lq ^ ((row >> 1) & 3)) << 3);
}

// ---------------------------------------------------------------------------
// prep: blocks 0-5 hist | rest: fp32->bf16 cvt (src=null -> zero fill)
// ---------------------------------------------------------------------------
struct CvtDesc { const float* src; bf16_t* dst; int n8; };
struct CvtBatch { CvtDesc d[13]; };

__global__ __launch_bounds__(256) void prep(const int* __restrict__ fpos,
                                            const int* __restrict__ tpos,
                                            int* __restrict__ CNT, CvtBatch cvb) {
  const int bid = blockIdx.x;
  const int tid = threadIdx.x;
  __shared__ int shist[NPOS];
  if (bid < 6) {
    const int b = bid >> 1, which = bid & 1;
    const int* src = (which ? tpos : fpos) + b * NIDX;
    for (int i = tid; i < NPOS; i += 256) shist[i] = 0;
    __syncthreads();
    for (int i = tid; i < NIDX; i += 256) atomicAdd(&shist[src[i] & (NPOS - 1)], 1);
    __syncthreads();
    for (int i = tid; i < NPOS; i += 256) CNT[bid * NPOS + i] = shist[i];
    return;
  }
  const CvtDesc de = cvb.d[(bid - 6) >> 6];
  for (int i = ((bid - 6) & 63) * 256 + tid; i < de.n8; i += 64 * 256) {
    bf16_t t[8];
    if (de.src) {
      const f32x4 a = *(const f32x4*)(de.src + (size_t)i * 8);
      const f32x4 b = *(const f32x4*)(de.src + (size_t)i * 8 + 4);
#pragma unroll
      for (int e = 0; e < 4; ++e) { t[e] = (bf16_t)a[e]; t[4 + e] = (bf16_t)b[e]; }
    } else {
#pragma unroll
      for (int e = 0; e < 8; ++e) t[e] = (bf16_t)0.f;
    }
    *(bf16x8*)(de.dst + (size_t)i * 8) = *(bf16x8*)t;
  }
}

// ---------------------------------------------------------------------------
// MFMA GEMM, 64x128 tile, dbuf single-barrier, swizzled staging.
// mode: 0 f32 out | 1 bf16 out | 2 bf16 transposed (C[c*512+r]) |
//       3 K-aug: c<768 -> bf16 C; 768<=c<784 -> f32 cb[r*16+c-768]
// ---------------------------------------------------------------------------
struct MDesc { const bf16_t* A; const bf16_t* B; const float* bias; void* C;
               float* cb; int mode; int ntiles; };
struct MBatch { MDesc d[18]; };

__global__ __launch_bounds__(256, 4) void gemm64(MBatch batch) {
  const MDesc de = batch.d[blockIdx.y];
  const int mt = blockIdx.x & 7, nt = blockIdx.x >> 3;   // 8 x up-to-7
  if (nt >= de.ntiles) return;
  const int m0 = mt * 64, n0 = nt * 128;

  __shared__ bf16_t SA[2][2048];   // [64][32] packed (swizzled chunks)
  __shared__ bf16_t SB[2][4096];   // [128][32]

  const int tid = threadIdx.x;
  const int w = tid >> 6, lane = tid & 63;
  const int wm = w >> 1, wn = w & 1;
  const int lm = lane & 15, lq = lane >> 4;
  const int sr = lane >> 2, sc = stg_chunk(lane);

  f32x4 acc[2][4] = {};

  auto stage = [&](int buf, int k0) {
#pragma unroll
    for (int c = 0; c < 3; ++c) {
      const int issue = w + c * 4;           // 0..11, wave-uniform
      if (issue < 4)
        g2lds16(de.A + (size_t)(m0 + issue * 16 + sr) * 768 + k0 + sc * 8,
                SA[buf] + issue * 512);
      else {
        const int e = issue - 4;
        g2lds16(de.B + (size_t)(n0 + e * 16 + sr) * 768 + k0 + sc * 8,
                SB[buf] + e * 512);
      }
    }
  };

  stage(0, 0);
  for (int k0i = 0; k0i < 24; ++k0i) {
    const int cur = k0i & 1;
    __syncthreads();
    if (k0i + 1 < 24) stage(cur ^ 1, (k0i + 1) * 32);
    bf16x8 af[2], bfr[4];
#pragma unroll
    for (int i = 0; i < 2; ++i)
      af[i] = *(const bf16x8*)(SA[cur] + rd_off(wm * 32 + i * 16 + lm, lq));
#pragma unroll
    for (int j = 0; j < 4; ++j)
      bfr[j] = *(const bf16x8*)(SB[cur] + rd_off(wn * 64 + j * 16 + lm, lq));
#pragma unroll
    for (int i = 0; i < 2; ++i)
#pragma unroll
      for (int j = 0; j < 4; ++j)
        acc[i][j] = __builtin_amdgcn_mfma_f32_16x16x32_bf16(af[i], bfr[j], acc[i][j], 0, 0, 0);
  }

#pragma unroll
  for (int i = 0; i < 2; ++i) {
    const int rbase = m0 + wm * 32 + i * 16 + lq * 4;
#pragma unroll
    for (int j = 0; j < 4; ++j) {
      const int c = n0 + wn * 64 + j * 16 + lm;
      const float bv = (de.bias && c < 768) ? de.bias[c] : 0.f;
#pragma unroll
      for (int r = 0; r < 4; ++r) {
        const float v = acc[i][j][r] + bv;
        if (de.mode == 0)      ((float*)de.C)[(size_t)(rbase + r) * 768 + c] = v;
        else if (de.mode == 1) ((bf16_t*)de.C)[(size_t)(rbase + r) * 768 + c] = (bf16_t)v;
        else if (de.mode == 2) ((bf16_t*)de.C)[(size_t)c * NPOS + rbase + r] = (bf16_t)v;
        else {
          if (c < 768)       ((bf16_t*)de.C)[(size_t)(rbase + r) * 768 + c] = (bf16_t)v;
          else if (c < 784)  de.cb[(size_t)(rbase + r) * 16 + (c - 768)] = v;
        }
      }
    }
  }
}

// ---------------------------------------------------------------------------
// Fused MFMA attention, single k-pass, head-sharing, VGPR-staged pipeline.
// Block = (pd, 2 heads, 32 f-rows), 512 threads / 8 waves.
// Wave w = (hh = w&1, jq = w>>1): S strip 32f x 128j in regs (64 VGPR).
// Per k0: next K/Q tile loaded into REGISTERS (async), current computed from
// LDS, regs->LDS at next iter top — global latency hidden behind compute.
// Then 2 head-phases: exp->P (U reused), PV MFMA with ones-row denominator;
// V tiles prefetched into regs across the phase barriers the same way.
// ---------------------------------------------------------------------------
__global__ __launch_bounds__(512, 4) void attn_mfma(
    const bf16_t* __restrict__ Qg, const bf16_t* __restrict__ Kg,
    const bf16_t* __restrict__ Vt, const float* __restrict__ cbG,
    const int* __restrict__ CNT, const float* __restrict__ mix0,
    const float* __restrict__ mix1, bf16_t* __restrict__ CTX) {
  const int bid = blockIdx.x;             // 6*8*16 = 768, pd-major
  const int pd = bid >> 7;
  const int hg = (bid >> 4) & 7;          // head group: heads hg*2, hg*2+1
  const int ft = bid & 15;
  const int dir = pd & 1;
  const int f0 = ft * 32;

  // U: k-loop staging { Q 32x32 @0 (1024 elems), K 512x32 @1024 (16384) }
  //    phase reuse:   P (32 x 532) = 17024 elems
  __shared__ bf16_t U[17408];
  __shared__ bf16_t Vs[64 * 264];         // [c-row][j], rows 0-47 V, 48 ones, 49+ zero
  __shared__ float mixs[2][768];          // pre-scaled by INV_SCALE
  __shared__ float cbw[2][512];           // cb*inv + log(cnt)
  __shared__ float rowl[2][32];

  const int tid = threadIdx.x;
  const int w = tid >> 6, lane = tid & 63;
  const int hh = w & 1, jq = w >> 1;
  const int lm = lane & 15, lq = lane >> 4;
  const int sr = lane >> 2, sc = stg_chunk(lane);

  const bf16_t* Qp = Qg + (size_t)pd * NPOS * DD;
  const bf16_t* Kp = Kg + (size_t)pd * NPOS * DD;
  const float* mixsel = dir ? mix1 : mix0;
  const int* cnt = CNT + ((pd & ~1) + (1 - dir)) * NPOS;  // to-side counts

  for (int i = tid; i < 2 * 768; i += 512) {
    const int h2 = i / 768, c = i % 768;
    mixs[h2][c] = mixsel[(hg * 2 + h2) * DD + c] * INV_SCALE;
  }
  for (int i = tid; i < 2 * 512; i += 512) {
    const int h2 = i >> 9, j = i & 511;
    cbw[h2][j] = cbG[((size_t)pd * NPOS + j) * HH + hg * 2 + h2] * INV_SCALE
               + __logf((float)cnt[j]);
  }
  // Vs static rows 48..63 (ones row + zero pad) — set once
  for (int i = tid; i < 16 * 264; i += 512) {
    const int r = 48 + i / 264, c = i % 264;
    Vs[r * 264 + c] = (bf16_t)((r == 48 && c < 256) ? 1.f : 0.f);
  }

  // ---- VGPR staging: wave w owns K issue-blocks w*4..w*4+3 at lane position
  //      'lane'; waves 0,1 additionally own Q issue-blocks 0,1. Layout is
  //      identical to the g2lds layout, so readers are unchanged. ----
  bf16x8 kreg[4];
  bf16x8 qreg;
  auto load_stage = [&](int k0) {
#pragma unroll
    for (int c = 0; c < 4; ++c) {
      const int e = w * 4 + c;
      kreg[c] = *(const bf16x8*)(Kp + (size_t)(e * 16 + sr) * DD + k0 + sc * 8);
    }
    if (w < 2)
      qreg = *(const bf16x8*)(Qp + (size_t)(f0 + w * 16 + sr) * DD + k0 + sc * 8);
  };
  auto write_stage = [&]() {
#pragma unroll
    for (int c = 0; c < 4; ++c) {
      const int e = w * 4 + c;
      *(bf16x8*)(U + 1024 + e * 512 + lane * 8) = kreg[c];
    }
    if (w < 2)
      *(bf16x8*)(U + w * 512 + lane * 8) = qreg;
  };

  f32x4 sa[2][8] = {};   // [f-frag][j-frag], wave strip 32f x 128j

  load_stage(0);
  for (int k0i = 0; k0i < 24; ++k0i) {
    const int k0 = k0i * 32;
    __syncthreads();                  // prev iter's LDS reads done (iter0: init)
    write_stage();                    // vmcnt wait here — covered by prev compute
    __syncthreads();                  // staging visible
    if (k0i + 1 < 24) load_stage(k0 + 32);   // async prefetch into regs

    const f32x4 mxa = *(const f32x4*)&mixs[hh][k0 + lq * 8];
    const f32x4 mxb = *(const f32x4*)&mixs[hh][k0 + lq * 8 + 4];
    bf16x8 af[2];
#pragma unroll
    for (int i = 0; i < 2; ++i) {
      const bf16x8 q = *(const bf16x8*)(U + rd_off(i * 16 + lm, lq));
      bf16_t t[8];
#pragma unroll
      for (int e = 0; e < 4; ++e) {
        t[e]     = (bf16_t)((float)q[e] * mxa[e]);
        t[4 + e] = (bf16_t)((float)q[4 + e] * mxb[e]);
      }
      af[i] = *(bf16x8*)t;
    }
#pragma unroll
    for (int jj = 0; jj < 8; ++jj) {
      const bf16x8 bf = *(const bf16x8*)(U + 1024 + rd_off(jq * 128 + jj * 16 + lm, lq));
      sa[0][jj] = __builtin_amdgcn_mfma_f32_16x16x32_bf16(af[0], bf, sa[0][jj], 0, 0, 0);
      sa[1][jj] = __builtin_amdgcn_mfma_f32_16x16x32_bf16(af[1], bf, sa[1][jj], 0, 0, 0);
    }
  }

  // ---- two head phases: exp -> P, PV with ones-row denominator ----
  const int fi = w & 1, cj = w >> 1;  // PV tile assignment (8 tiles: 2f x 4c)
  const bf16_t* Vp0 = Vt + (size_t)pd * DD * NPOS + (size_t)(hg * 2) * DHH * NPOS;
  const bf16_t* Vp1 = Vp0 + (size_t)DHH * NPOS;

  bf16x8 vreg[3];                     // V prefetch: 48x32 16B-slots / 512 thr = 3
  auto load_vs = [&](const bf16_t* Vp, int vh) {
#pragma unroll
    for (int u = 0; u < 3; ++u) {
      const int s = tid + u * 512, r = s >> 5, cc = s & 31;
      vreg[u] = *(const bf16x8*)(Vp + (size_t)r * NPOS + vh * 256 + cc * 8);
    }
  };
  auto write_vs = [&]() {
#pragma unroll
    for (int u = 0; u < 3; ++u) {
      const int s = tid + u * 512, r = s >> 5, cc = s & 31;
      *(bf16x8*)(Vs + r * 264 + cc * 8) = vreg[u];
    }
  };

  load_vs(Vp0, 0);
  f32x4 pv[2] = {};

  for (int ph = 0; ph < 2; ++ph) {
    for (int vh = 0; vh < 2; ++vh) {
      __syncthreads();                // prev consumers of U/Vs done
      write_vs();
      if (hh == ph && vh == 0) {      // owner waves write P = exp(sa + cbw)
#pragma unroll
        for (int jj = 0; jj < 8; ++jj) {
          const int col = jq * 128 + jj * 16 + lm;
          const float cb = cbw[ph][col];
#pragma unroll
          for (int i = 0; i < 2; ++i) {
            const int rb = i * 16 + lq * 4;
#pragma unroll
            for (int r = 0; r < 4; ++r)
              U[(rb + r) * 532 + col] = (bf16_t)__expf(sa[i][jj][r] + cb);
          }
        }
      }
      __syncthreads();                // P + Vs visible
      if (ph == 0 && vh == 0)      load_vs(Vp0, 1);
      else if (ph == 0 && vh == 1) load_vs(Vp1, 0);
      else if (ph == 1 && vh == 0) load_vs(Vp1, 1);
#pragma unroll
      for (int kk = 0; kk < 8; ++kk) {
        const bf16x8 pa = *(const bf16x8*)(U + (fi * 16 + lm) * 532 + vh * 256 + kk * 32 + lq * 8);
        const bf16x8 pb = *(const bf16x8*)(Vs + (cj * 16 + lm) * 264 + kk * 32 + lq * 8);
        pv[ph] = __builtin_amdgcn_mfma_f32_16x16x32_bf16(pa, pb, pv[ph], 0, 0, 0);
      }
    }
    if (cj == 3 && lm == 0) {         // col 48 = row denominator
#pragma unroll
      for (int r = 0; r < 4; ++r) rowl[ph][fi * 16 + lq * 4 + r] = pv[ph][r];
    }
  }
  __syncthreads();

  // ---- epilogue: ctx = pv / l ----
  if (cj < 3) {
#pragma unroll
    for (int ph = 0; ph < 2; ++ph) {
      const int h = hg * 2 + ph;
#pragma unroll
      for (int r = 0; r < 4; ++r) {
        const int fr = fi * 16 + lq * 4 + r;
        CTX[((size_t)pd * NPOS + f0 + fr) * DD + h * DHH + cj * 16 + lm] =
            (bf16_t)(pv[ph][r] / rowl[ph][fr]);
      }
    }
  }
}

// ---------------------------------------------------------------------------
// Residual + LayerNorm + count-weighted mean -> out[b][dir*768 .. +768]
// ---------------------------------------------------------------------------
__global__ __launch_bounds__(256) void ln_mean_kernel(
    const float* __restrict__ hs, const float* __restrict__ XB,
    const int* __restrict__ CNT,
    const float* __restrict__ lng0, const float* __restrict__ lnb0,
    const float* __restrict__ lng1, const float* __restrict__ lnb1,
    float* __restrict__ out) {
  const int blk = blockIdx.x;          // (b*2+dir)*64 + chunk, 384 blocks
  const int chunk = blk & 63;
  const int pd = blk >> 6;
  const int b = pd >> 1, dir = pd & 1;
  const float* lng = dir ? lng1 : lng0;
  const float* lnb = dir ? lnb1 : lnb0;
  const int* cnt = CNT + pd * NPOS;    // from-side counts
  const float* hb = hs + (size_t)b * NPOS * DD;
  const float* xb = XB + (size_t)pd * NPOS * DD;

  __shared__ float wacc[4][DD];
  const int tid = threadIdx.x;
  const int wave = tid >> 6, lane = tid & 63;
  for (int d0 = tid; d0 < 4 * DD; d0 += 256) ((float*)wacc)[d0] = 0.f;
  __syncthreads();

  float lg[12], lb[12];
#pragma unroll
  for (int qd = 0; qd < 12; ++qd) {
    lg[qd] = lng[lane + qd * 64];
    lb[qd] = lnb[lane + qd * 64];
  }

  for (int rr = 0; rr < 2; ++rr) {
    const int p = chunk * 8 + wave * 2 + rr;
    float x[12];
    float s = 0.f, ss = 0.f;
#pragma unroll
    for (int qd = 0; qd < 12; ++qd) {
      const int d0 = lane + qd * 64;
      const float xv = hb[(size_t)p * DD + d0] + xb[(size_t)p * DD + d0];
      x[qd] = xv; s += xv; ss += xv * xv;
    }
#pragma unroll
    for (int o = 1; o < 64; o <<= 1) {
      s += __shfl_xor(s, o);
      ss += __shfl_xor(ss, o);
    }
    const float mu = s * (1.f / 768.f);
    const float var = ss * (1.f / 768.f) - mu * mu;
    const float rstd = rsqrtf(var + LN_EPS);
    const float wgt = (float)cnt[p];
    if (wgt != 0.f) {
#pragma unroll
      for (int qd = 0; qd < 12; ++qd) {
        const int d0 = lane + qd * 64;
        wacc[wave][d0] += wgt * (lg[qd] * (x[qd] - mu) * rstd + lb[qd]);
      }
    }
  }
  __syncthreads();
  for (int d0 = tid; d0 < DD; d0 += 256) {
    const float t = wacc[0][d0] + wacc[1][d0] + wacc[2][d0] + wacc[3][d0];
    atomicAdd(&out[b * 1536 + dir * 768 + d0], t * (1.f / 2048.f));
  }
}

// ---------------------------------------------------------------------------
extern "C" void kernel_launch(void* const* d_in, const int* in_sizes, int n_in,
                              void* d_out, int out_size, void* d_ws, size_t ws_size,
                              hipStream_t stream) {
  const float* hs  = (const float*)d_in[0];
  const int* fpos  = (const int*)d_in[1];
  const int* tpos  = (const int*)d_in[2];

  const float* Wq[2]; const float* Wk[2]; const float* Wcb[2]; const float* Wv[2];
  const float* Wd[2]; const float* mixp[2];
  const float* bv[2]; const float* bd[2]; const float* lng[2]; const float* lnb[2];
  for (int p = 0; p < 2; ++p) {
    const int base = 3 + p * 10;
    Wq[p]   = (const float*)d_in[base + 0];
    Wk[p]   = (const float*)d_in[base + 1];
    Wcb[p]  = (const float*)d_in[base + 2];
    Wv[p]   = (const float*)d_in[base + 3];
    Wd[p]   = (const float*)d_in[base + 4];
    mixp[p] = (const float*)d_in[base + 5];
    bv[p]   = (const float*)d_in[base + 6];
    bd[p]   = (const float*)d_in[base + 7];
    lng[p]  = (const float*)d_in[base + 8];
    lnb[p]  = (const float*)d_in[base + 9];
  }

  char* wsp = (char*)d_ws;
  size_t off = 0;
  auto alloc = [&](size_t bytes) { char* p = wsp + off; off = (off + bytes + 255) & ~(size_t)255; return p; };
  bf16_t* hsb  = (bf16_t*)alloc((size_t)3 * NPOS * DD * 2);
  bf16_t* Wb   = (bf16_t*)alloc((size_t)6 * DD * DD * 2);     // Wq0,Wv0,Wd0,Wq1,Wv1,Wd1
  bf16_t* WkCb = (bf16_t*)alloc((size_t)2 * 896 * DD * 2);    // [Wk;Wcb;pad] per pset
  bf16_t* Qbf  = (bf16_t*)alloc((size_t)6 * NPOS * DD * 2);
  bf16_t* Kbf  = (bf16_t*)alloc((size_t)6 * NPOS * DD * 2);
  bf16_t* VtG  = (bf16_t*)alloc((size_t)6 * DD * NPOS * 2);
  bf16_t* CTXb = (bf16_t*)alloc((size_t)6 * NPOS * DD * 2);
  float*  XB   = (float*) alloc((size_t)6 * NPOS * DD * 4);
  float*  cbG  = (float*) alloc((size_t)6 * NPOS * HH * 4);
  int*    CNTb = (int*)   alloc((size_t)6 * NPOS * 4);

  hipMemsetAsync(d_out, 0, (size_t)out_size * sizeof(float), stream);

  CvtBatch cvb{};
  cvb.d[0] = CvtDesc{hs, hsb, 3 * NPOS * DD / 8};
  for (int p = 0; p < 2; ++p) {
    cvb.d[1 + p * 3] = CvtDesc{Wq[p], Wb + (size_t)(p * 3 + 0) * DD * DD, DD * DD / 8};
    cvb.d[2 + p * 3] = CvtDesc{Wv[p], Wb + (size_t)(p * 3 + 1) * DD * DD, DD * DD / 8};
    cvb.d[3 + p * 3] = CvtDesc{Wd[p], Wb + (size_t)(p * 3 + 2) * DD * DD, DD * DD / 8};
    bf16_t* wk = WkCb + (size_t)p * 896 * DD;
    cvb.d[7 + p * 3] = CvtDesc{Wk[p], wk, DD * DD / 8};
    cvb.d[8 + p * 3] = CvtDesc{Wcb[p], wk + (size_t)768 * DD, 16 * DD / 8};
    cvb.d[9 + p * 3] = CvtDesc{nullptr, wk + (size_t)784 * DD, 112 * DD / 8};
  }
  prep<<<838, 256, 0, stream>>>(fpos, tpos, CNTb, cvb);

  // projection GEMMs: Q bf16, K' (K + content bias), V bf16-transposed
  MBatch gb{};
  int n = 0;
  for (int b = 0; b < 3; ++b)
    for (int p = 0; p < 2; ++p) {
      const int pd = b * 2 + p;
      const bf16_t* A = hsb + (size_t)b * NPOS * DD;
      const size_t o = (size_t)pd * NPOS * DD;
      gb.d[n++] = MDesc{A, Wb + (size_t)(p * 3 + 0) * DD * DD, nullptr, Qbf + o, nullptr, 1, 6};
      gb.d[n++] = MDesc{A, WkCb + (size_t)p * 896 * DD, nullptr, Kbf + o,
                        cbG + (size_t)pd * NPOS * HH, 3, 7};
      gb.d[n++] = MDesc{A, Wb + (size_t)(p * 3 + 1) * DD * DD, bv[p],
                        VtG + (size_t)pd * DD * NPOS, nullptr, 2, 6};
    }
  gemm64<<<dim3(56, 18), 256, 0, stream>>>(gb);

  attn_mfma<<<768, 512, 0, stream>>>(Qbf, Kbf, VtG, cbG, CNTb, mixp[0], mixp[1], CTXb);

  MBatch gd{};
  for (int b = 0; b < 3; ++b)
    for (int p = 0; p < 2; ++p) {
      const int pd = b * 2 + p;
      const size_t o = (size_t)pd * NPOS * DD;
      gd.d[pd] = MDesc{CTXb + o, Wb + (size_t)(p * 3 + 2) * DD * DD, bd[p],
                       XB + o, nullptr, 0, 6};
    }
  gemm64<<<dim3(56, 6), 256, 0, stream>>>(gd);

  ln_mean_kernel<<<384, 256, 0, stream>>>(hs, XB, CNTb, lng[0], lnb[0], lng[1], lnb[1],
                                          (float*)d_out);
}